// Round 6
// baseline (1711.084 us; speedup 1.0000x reference)
//
#include <hip/hip_runtime.h>
#include <hip/hip_bf16.h>

#define N_ATOMS 25000
#define N_PAIRS 500000
#define DEPTH 4
#define TILE 192
#define PTHREADS 768
#define SENT 0x7fffffff

typedef _Float16 f16x8 __attribute__((ext_vector_type(8)));
typedef float f32x16 __attribute__((ext_vector_type(16)));
typedef unsigned short u16;
typedef unsigned int u32;

__device__ __forceinline__ float tanh_fast(float x) {
    // tanh(x) = 1 - 2/(exp(2x)+1); saturates correctly at +/-inf
    float e = __expf(2.0f * x);
    return 1.0f - 2.0f * __builtin_amdgcn_rcpf(e + 1.0f);
}

__device__ __forceinline__ void split_h(float x, u16& hi, u16& lo) {
    _Float16 h = (_Float16)x;                 // RNE
    _Float16 l = (_Float16)(x - (float)h);    // residual, RNE
    hi = *(u16*)&h;
    lo = *(u16*)&l;
}

// LDS bank-swizzle on 16B-unit index (involution within 128B block).
// Verified: SQ_LDS_BANK_CONFLICT 2.02e7 -> 0 (rounds 1-3).
__device__ __forceinline__ int swz8(int u) { return u ^ ((u >> 5) & 7); }

// ---------------- prep: split weights to hi/lo fp16, fragment-major images
__global__ __launch_bounds__(256)
void prep_kernel(const float* __restrict__ piW1, const float* __restrict__ piW2,
                 const float* __restrict__ iiW1, const float* __restrict__ iiW2,
                 u16* __restrict__ img1, u16* __restrict__ img2, u16* __restrict__ imgab) {
    int gid = blockIdx.x * 256 + threadIdx.x;
    int d = gid >> 15, e = gid & 32767;
    u16 hi, lo;
    if (e < 8192) {                 // W1 [k=128][n=64] (unused by pair since R5)
        int k = e >> 6, n = e & 63;
        split_h(piW1[d * 8192 + e], hi, lo);
        int ntw = n >> 5, colb = n & 31;
        int ks = k >> 4, lh = (k >> 3) & 1, j = k & 7;
        int off = ((ntw * 8 + ks) * 64 + lh * 32 + colb) * 8 + j;
        img1[d * 16384 + 0 * 8192 + off] = hi;
        img1[d * 16384 + 1 * 8192 + off] = lo;
    } else if (e < 24576) {         // W2 [k=64][n=256], permuted n = 4*ch + t
        int s = e - 8192;
        int k = s >> 8, n = s & 255;
        split_h(piW2[d * 16384 + s], hi, lo);
        int ch = n >> 2, t = n & 3;
        int ntw = ch >> 5, colb = ch & 31;
        int ks = k >> 4, lh = (k >> 3) & 1, j = k & 7;
        int off = (((ntw * 4 + t) * 4 + ks) * 64 + lh * 32 + colb) * 8 + j;
        img2[d * 32768 + 0 * 16384 + off] = hi;
        img2[d * 32768 + 1 * 16384 + off] = lo;
    } else {                        // Wa (stage0) / Wb (stage1), [k=64][n=64]
        int stage = (e < 28672) ? 0 : 1;
        int s = e - (stage ? 28672 : 24576);
        int k = s >> 6, n = s & 63;
        float x = stage ? iiW2[d * 4096 + s] : iiW1[d * 4096 + s];
        split_h(x, hi, lo);
        int ntw = n >> 5, colb = n & 31;
        int ks = k >> 4, lh = (k >> 3) & 1, j = k & 7;
        int off = ((ntw * 4 + ks) * 64 + lh * 32 + colb) * 8 + j;
        imgab[d * 16384 + (stage * 2 + 0) * 4096 + off] = hi;
        imgab[d * 16384 + (stage * 2 + 1) * 4096 + off] = lo;
    }
}

__global__ __launch_bounds__(256)
void prep_b2(const float* __restrict__ piB2, float* __restrict__ b2p) {
    int d = blockIdx.x, n = threadIdx.x;
    int ch = n >> 2, t = n & 3;
    int np = (ch >> 5) * 128 + t * 32 + (ch & 31);
    b2p[d * 256 + np] = piB2[d * 256 + n];
}

// ---------------- counting sort of pairs by ind_i (once per launch; reused all depths)
__global__ __launch_bounds__(256)
void zero_hist(u32* __restrict__ hist) {
    int i = blockIdx.x * 256 + threadIdx.x;
    if (i < 25024) hist[i] = 0u;
}

__global__ __launch_bounds__(256)
void hist_kernel(const int* __restrict__ ind2, u32* __restrict__ hist) {
    int p = blockIdx.x * 256 + threadIdx.x;
    if (p < N_PAIRS) atomicAdd(&hist[ind2[2 * p]], 1u);
}

__global__ __launch_bounds__(1024)
void scan_kernel(const u32* __restrict__ hist, u32* __restrict__ cursor) {
    __shared__ u32 sdata[1024];
    __shared__ u32 stotal;
    int t = threadIdx.x;
    if (t == 0) stotal = 0u;
    __syncthreads();
    for (int cch = 0; cch < 25; ++cch) {     // 25*1024 >= 25000
        int idx = cch * 1024 + t;
        u32 v = (idx < N_ATOMS) ? hist[idx] : 0u;
        sdata[t] = v;
        __syncthreads();
        for (int off = 1; off < 1024; off <<= 1) {
            u32 x = (t >= off) ? sdata[t - off] : 0u;
            __syncthreads();
            sdata[t] += x;
            __syncthreads();
        }
        u32 excl = sdata[t] - v;
        u32 tot = stotal;
        if (idx < N_ATOMS) cursor[idx] = tot + excl;
        u32 chunktot = sdata[1023];
        __syncthreads();
        if (t == 0) stotal = tot + chunktot;
        __syncthreads();
    }
}

__global__ __launch_bounds__(256)
void scatter_kernel(const int* __restrict__ ind2, const float* __restrict__ basis,
                    u32* __restrict__ cursor, int2* __restrict__ sIJ,
                    float4* __restrict__ sBas4) {
    int p = blockIdx.x * 256 + threadIdx.x;
    if (p >= N_PAIRS) return;
    int i = ind2[2 * p], j = ind2[2 * p + 1];
    u32 pos = atomicAdd(&cursor[i], 1u);
    sIJ[pos] = make_int2(i, j);
    sBas4[pos] = ((const float4*)basis)[p];
}

// ---------------- atom-level MLP: 16 atoms/block, 4 atoms/thread (weight reuse x4)
template <int K, bool IS_D0>
__global__ __launch_bounds__(256)
void atom_mlp(const float* __restrict__ p_in,
              const float* __restrict__ W1, const float* __restrict__ b1,
              const float* __restrict__ W2, const float* __restrict__ b2,
              const float* __restrict__ res0_w,
              const float* __restrict__ piW1d,
              float* __restrict__ Uo, float* __restrict__ Vo,
              float* __restrict__ acc_out) {
    __shared__ float sP[16][K];
    __shared__ float sH[16][64];
    int tid = threadIdx.x, q = tid >> 6, c = tid & 63;
    int abase = blockIdx.x * 16;
    for (int idx = tid; idx < 16 * K; idx += 256) {
        int ar = idx / K, kc = idx - ar * K;
        int a = abase + ar;
        sP[ar][kc] = (a < N_ATOMS) ? p_in[a * K + kc] : 0.f;
    }
    __syncthreads();
    float s[4];
#pragma unroll
    for (int i = 0; i < 4; ++i) s[i] = b1[c];
#pragma unroll
    for (int k = 0; k < K; ++k) {
        float wv = W1[k * 64 + c];
#pragma unroll
        for (int i = 0; i < 4; ++i) s[i] += sP[q * 4 + i][k] * wv;
    }
    float r[4];
    if (IS_D0) {
#pragma unroll
        for (int i = 0; i < 4; ++i) r[i] = 0.f;
#pragma unroll
        for (int k = 0; k < 16; ++k) {
            float wv = res0_w[k * 64 + c];
#pragma unroll
            for (int i = 0; i < 4; ++i) r[i] += sP[q * 4 + i][k] * wv;
        }
    } else {
#pragma unroll
        for (int i = 0; i < 4; ++i) r[i] = sP[q * 4 + i][c];
    }
#pragma unroll
    for (int i = 0; i < 4; ++i) {
        int a = abase + q * 4 + i;
        if (a < N_ATOMS) acc_out[a * 64 + c] = r[i];
        sH[q * 4 + i][c] = tanh_fast(s[i]);
    }
    __syncthreads();
    float s2[4];
#pragma unroll
    for (int i = 0; i < 4; ++i) s2[i] = b2[c];
#pragma unroll
    for (int k = 0; k < 64; ++k) {
        float wv = W2[k * 64 + c];
#pragma unroll
        for (int i = 0; i < 4; ++i) s2[i] += sH[q * 4 + i][k] * wv;
    }
    __syncthreads();
#pragma unroll
    for (int i = 0; i < 4; ++i) sH[q * 4 + i][c] = tanh_fast(s2[i]);
    __syncthreads();
    float su[4] = {0.f, 0.f, 0.f, 0.f}, sv[4] = {0.f, 0.f, 0.f, 0.f};
#pragma unroll
    for (int k = 0; k < 64; ++k) {
        float wu = piW1d[k * 64 + c];
        float wv2 = piW1d[(64 + k) * 64 + c];
#pragma unroll
        for (int i = 0; i < 4; ++i) {
            float x = sH[q * 4 + i][k];
            su[i] += x * wu;
            sv[i] += x * wv2;
        }
    }
#pragma unroll
    for (int i = 0; i < 4; ++i) {
        int a = abase + q * 4 + i;
        if (a < N_ATOMS) { Uo[a * 64 + c] = su[i]; Vo[a * 64 + c] = sv[i]; }
    }
}

// ---------------- output head (fp32), standalone (after last depth), 16 atoms/block
__global__ __launch_bounds__(256)
void out_kernel(const float* __restrict__ p,
                const float* __restrict__ W1, const float* __restrict__ b1,
                const float* __restrict__ W2, const float* __restrict__ b2,
                const float* __restrict__ wo,
                float* __restrict__ out, int store) {
    __shared__ float sP[16][64];
    __shared__ float sH[16][64];
    int tid = threadIdx.x, q = tid >> 6, c = tid & 63;
    int abase = blockIdx.x * 16;
    for (int idx = tid; idx < 1024; idx += 256) {
        int ar = idx >> 6, kc = idx & 63;
        int a = abase + ar;
        sP[ar][kc] = (a < N_ATOMS) ? p[a * 64 + kc] : 0.f;
    }
    __syncthreads();
    float s[4];
#pragma unroll
    for (int i = 0; i < 4; ++i) s[i] = b1[c];
#pragma unroll
    for (int k = 0; k < 64; ++k) {
        float wv = W1[k * 64 + c];
#pragma unroll
        for (int i = 0; i < 4; ++i) s[i] += sP[q * 4 + i][k] * wv;
    }
#pragma unroll
    for (int i = 0; i < 4; ++i) sH[q * 4 + i][c] = tanh_fast(s[i]);
    __syncthreads();
    float s2[4];
#pragma unroll
    for (int i = 0; i < 4; ++i) s2[i] = b2[c];
#pragma unroll
    for (int k = 0; k < 64; ++k) {
        float wv = W2[k * 64 + c];
#pragma unroll
        for (int i = 0; i < 4; ++i) s2[i] += sH[q * 4 + i][k] * wv;
    }
    float woc = wo[c];
#pragma unroll
    for (int i = 0; i < 4; ++i) {
        float v = tanh_fast(s2[i]) * woc;
#pragma unroll
        for (int off = 32; off > 0; off >>= 1) v += __shfl_down(v, off, 64);
        if (c == 0) {
            int a = abase + q * 4 + i;
            if (a < N_ATOMS) { if (store) out[a] = v; else out[a] += v; }
        }
    }
}

// ---------------- fused: out head of depth d + atom MLP of depth d+1 (+U/V emit)
__global__ __launch_bounds__(256)
void fused_out_atom(const float* __restrict__ p,
                    const float* __restrict__ oW1, const float* __restrict__ ob1,
                    const float* __restrict__ oW2, const float* __restrict__ ob2,
                    const float* __restrict__ wo,
                    const float* __restrict__ aW1, const float* __restrict__ ab1,
                    const float* __restrict__ aW2, const float* __restrict__ ab2,
                    float* __restrict__ out, int store,
                    const float* __restrict__ piW1d,
                    float* __restrict__ Uo, float* __restrict__ Vo,
                    float* __restrict__ acc_out) {
    __shared__ float sP[16][64];
    __shared__ float sHo[16][64];
    __shared__ float sHa[16][64];
    int tid = threadIdx.x, q = tid >> 6, c = tid & 63;
    int abase = blockIdx.x * 16;
    for (int idx = tid; idx < 1024; idx += 256) {
        int ar = idx >> 6, kc = idx & 63;
        int a = abase + ar;
        float pv = (a < N_ATOMS) ? p[a * 64 + kc] : 0.f;
        sP[ar][kc] = pv;
        if (a < N_ATOMS) acc_out[a * 64 + kc] = pv;   // residual base for next depth
    }
    __syncthreads();
    float so[4], sa[4];
#pragma unroll
    for (int i = 0; i < 4; ++i) { so[i] = ob1[c]; sa[i] = ab1[c]; }
#pragma unroll
    for (int k = 0; k < 64; ++k) {
        float w1o = oW1[k * 64 + c];
        float w1a = aW1[k * 64 + c];
#pragma unroll
        for (int i = 0; i < 4; ++i) {
            float x = sP[q * 4 + i][k];
            so[i] += x * w1o;
            sa[i] += x * w1a;
        }
    }
#pragma unroll
    for (int i = 0; i < 4; ++i) {
        sHo[q * 4 + i][c] = tanh_fast(so[i]);
        sHa[q * 4 + i][c] = tanh_fast(sa[i]);
    }
    __syncthreads();
    float s2o[4], s2a[4];
#pragma unroll
    for (int i = 0; i < 4; ++i) { s2o[i] = ob2[c]; s2a[i] = ab2[c]; }
#pragma unroll
    for (int k = 0; k < 64; ++k) {
        float w2o = oW2[k * 64 + c];
        float w2a = aW2[k * 64 + c];
#pragma unroll
        for (int i = 0; i < 4; ++i) {
            s2o[i] += sHo[q * 4 + i][k] * w2o;
            s2a[i] += sHa[q * 4 + i][k] * w2a;
        }
    }
    float woc = wo[c];
#pragma unroll
    for (int i = 0; i < 4; ++i) {
        float v = tanh_fast(s2o[i]) * woc;
#pragma unroll
        for (int off = 32; off > 0; off >>= 1) v += __shfl_down(v, off, 64);
        if (c == 0) {
            int a = abase + q * 4 + i;
            if (a < N_ATOMS) { if (store) out[a] = v; else out[a] += v; }
        }
    }
    __syncthreads();
#pragma unroll
    for (int i = 0; i < 4; ++i) sHo[q * 4 + i][c] = tanh_fast(s2a[i]);
    __syncthreads();
    float su[4] = {0.f, 0.f, 0.f, 0.f}, sv[4] = {0.f, 0.f, 0.f, 0.f};
#pragma unroll
    for (int k = 0; k < 64; ++k) {
        float wu = piW1d[k * 64 + c];
        float wv2 = piW1d[(64 + k) * 64 + c];
#pragma unroll
        for (int i = 0; i < 4; ++i) {
            float x = sHo[q * 4 + i][k];
            su[i] += x * wu;
            sv[i] += x * wv2;
        }
    }
#pragma unroll
    for (int i = 0; i < 4; ++i) {
        int a = abase + q * 4 + i;
        if (a < N_ATOMS) { Uo[a * 64 + c] = su[i]; Vo[a * 64 + c] = sv[i]; }
    }
}

// ---------------- pair pipeline v3: sorted pairs, segment-reduced scatter
#define MFMA __builtin_amdgcn_mfma_f32_32x32x16_f16

__global__ __launch_bounds__(PTHREADS, 3)
void pair_kernel(const float* __restrict__ Uin,
                 const float* __restrict__ Vin,
                 const int2* __restrict__ sIJ,
                 const float4* __restrict__ sBas4,
                 const u16* __restrict__ img2,
                 const u16* __restrict__ imgab,
                 const float* __restrict__ piB1,
                 const float* __restrict__ b2p,
                 float* __restrict__ accp) {
    __shared__ __attribute__((aligned(16))) _Float16 sW2[32768];   // 64 KB
    __shared__ __attribute__((aligned(16))) u16 sAB[16384];        // 32 KB
    __shared__ __attribute__((aligned(16))) _Float16 bufs[24576];  // 48 KB: bufA|bufB, fval f32 view
    __shared__ float sBas[TILE * 4];                               //  3 KB
    __shared__ int sIdx[TILE];                                     // 0.75 KB
    __shared__ unsigned short leadRow[TILE];                       // 0.38 KB
    __shared__ int nLead;
    // total ~148 KB -> 1 block/CU, 12 waves = 3 waves/SIMD

    const int tid = threadIdx.x;
    for (int i = tid; i < 4096; i += PTHREADS) ((uint4*)sW2)[i] = ((const uint4*)img2)[i];
    for (int i = tid; i < 2048; i += PTHREADS) ((uint4*)sAB)[i] = ((const uint4*)imgab)[i];

    char* bufA = (char*)bufs;
    char* bufB = (char*)bufs + 24576;
    float* fval = (float*)bufs;            // [192][64] rotated: fval[r*64 + ((ch+r)&63)]

    const int l = tid & 63;
    const int w = tid >> 6;
    const int mt = w >> 1, ntw = w & 1;
    const int col = l & 31, kg = l >> 5;
    const int ch = ntw * 32 + col;
    const int chks = ch >> 4, chlh = (ch >> 3) & 1, chj = ch & 7;

    int rb[4], wb[4];
    {
        const int wxor = 2 * chks + chlh;
#pragma unroll
        for (int c = 0; c < 4; ++c) {
            rb[c] = (l ^ (kg + 2 * c)) << 4;
            wb[c] = (mt * 4 + chks) * 1024 + chlh * 512 + ((((c) + 4 * kg) ^ wxor) << 4) + chj * 2;
        }
    }
    const int mts = mt << 12;

    const int m = tid >> 2, ksel = tid & 3;
    const int mtd = m >> 5, lrow = m & 31;
    const int u0 = (mtd * 4 + ksel) * 64 + lrow;
    const int wA0 = swz8(u0) * 16, wA1 = swz8(u0 + 32) * 16;

    float b1p[16];
#pragma unroll
    for (int z = 0; z < 16; ++z) b1p[z] = piB1[ksel * 16 + z];
    float b2v[4];
#pragma unroll
    for (int t = 0; t < 4; ++t) b2v[t] = b2p[ntw * 128 + t * 32 + col];

    const int nTiles = (N_PAIRS + TILE - 1) / TILE;

    float ur[16], vr[16];
    auto loadUV = [&](int tile) {
        int p = tile * TILE + m;
        bool ok = (p < N_PAIRS);
        int2 ij = ok ? sIJ[p] : make_int2(0, 0);
        const float* up = Uin + ij.x * 64 + ksel * 16;
        const float* vp = Vin + ij.y * 64 + ksel * 16;
        float4 z4 = make_float4(0.f, 0.f, 0.f, 0.f);
#pragma unroll
        for (int q = 0; q < 4; ++q) {
            float4 a = ok ? *(const float4*)(up + q * 4) : z4;
            float4 b = ok ? *(const float4*)(vp + q * 4) : z4;
            ur[q * 4 + 0] = a.x; ur[q * 4 + 1] = a.y; ur[q * 4 + 2] = a.z; ur[q * 4 + 3] = a.w;
            vr[q * 4 + 0] = b.x; vr[q * 4 + 1] = b.y; vr[q * 4 + 2] = b.z; vr[q * 4 + 3] = b.w;
        }
    };
    loadUV(blockIdx.x);

    for (int tile = blockIdx.x; tile < nTiles; tile += gridDim.x) {
        const int base = tile * TILE;

        // ---- P1: stage basis/sorted-i; G1out = tanh(U[i]+V[j]+b1) -> bufA frags
        if (tid < TILE) {
            int p = base + tid;
            bool ok = p < N_PAIRS;
            float4 bv = ok ? sBas4[p] : make_float4(0.f, 0.f, 0.f, 0.f);
            *(float4*)&sBas[tid * 4] = bv;
            sIdx[tid] = ok ? sIJ[p].x : SENT;
        }
        if (tid == 255) nLead = 0;
        {
            f16x8 lo8, hi8;
#pragma unroll
            for (int z = 0; z < 8; ++z)
                lo8[z] = (_Float16)tanh_fast(ur[z] + vr[z] + b1p[z]);
#pragma unroll
            for (int z = 0; z < 8; ++z)
                hi8[z] = (_Float16)tanh_fast(ur[8 + z] + vr[8 + z] + b1p[8 + z]);
            *(f16x8*)(bufA + wA0) = lo8;
            *(f16x8*)(bufA + wA1) = hi8;
        }
        __syncthreads();

        // ---- P2: build segment-leader list; [192x64]@[64x256]+b2, tanh, basis contraction -> bufB
        if (tid < TILE) {
            int id = sIdx[tid];
            if (tid == 0 || id != sIdx[tid - 1]) {
                int k = atomicAdd(&nLead, 1);
                leadRow[k] = (unsigned short)tid;
            }
        }
        {
            f16x8 afr[4];
#pragma unroll
            for (int ks = 0; ks < 4; ++ks)
                afr[ks] = *(const f16x8*)(bufA + mts + ks * 1024 + rb[ks]);
            float s[16];
#pragma unroll
            for (int r = 0; r < 16; ++r) s[r] = 0.f;
#pragma unroll
            for (int pp = 0; pp < 2; ++pp) {
                f32x16 a0 = {}, a1 = {};
                const int t0 = 2 * pp, t1 = 2 * pp + 1;
#pragma unroll
                for (int ks = 0; ks < 4; ++ks) {
                    a0 = MFMA(afr[ks], *(const f16x8*)(sW2 + ((ntw * 4 + t0) * 4 + ks) * 512 + l * 8), a0, 0, 0, 0);
                    a0 = MFMA(afr[ks], *(const f16x8*)(sW2 + 16384 + ((ntw * 4 + t0) * 4 + ks) * 512 + l * 8), a0, 0, 0, 0);
                    a1 = MFMA(afr[ks], *(const f16x8*)(sW2 + ((ntw * 4 + t1) * 4 + ks) * 512 + l * 8), a1, 0, 0, 0);
                    a1 = MFMA(afr[ks], *(const f16x8*)(sW2 + 16384 + ((ntw * 4 + t1) * 4 + ks) * 512 + l * 8), a1, 0, 0, 0);
                }
#pragma unroll
                for (int r = 0; r < 16; ++r) {
                    int lr2 = (r & 3) + 8 * (r >> 2) + 4 * kg;
                    int row = mt * 32 + lr2;
                    float2 bb = *(const float2*)&sBas[row * 4 + 2 * pp];
                    s[r] += tanh_fast(a0[r] + b2v[t0]) * bb.x + tanh_fast(a1[r] + b2v[t1]) * bb.y;
                }
            }
#pragma unroll
            for (int r = 0; r < 16; ++r)
                *(u16*)(bufB + wb[r & 3] + ((r >> 2) << 7)) =
                    __builtin_bit_cast(u16, (_Float16)s[r]);
        }
        __syncthreads();

        // ---- P3: inter @ ii_w1 (hi+lo), tanh -> bufA
        {
            f32x16 ah = {}, al2 = {};
#pragma unroll
            for (int ks = 0; ks < 4; ++ks) {
                f16x8 a = *(const f16x8*)(bufB + mts + ks * 1024 + rb[ks]);
                ah  = MFMA(a, *(const f16x8*)(sAB + 0 * 4096 + ntw * 2048 + ks * 512 + l * 8), ah, 0, 0, 0);
                al2 = MFMA(a, *(const f16x8*)(sAB + 1 * 4096 + ntw * 2048 + ks * 512 + l * 8), al2, 0, 0, 0);
            }
#pragma unroll
            for (int r = 0; r < 16; ++r)
                *(u16*)(bufA + wb[r & 3] + ((r >> 2) << 7)) =
                    __builtin_bit_cast(u16, (_Float16)tanh_fast(ah[r] + al2[r]));
        }
        __syncthreads();

        // ---- P4: @ ii_w2, tanh -> f32 LDS tile (rotated); prefetch next-tile U/V
        {
            f16x8 afr[4];
#pragma unroll
            for (int ks = 0; ks < 4; ++ks)
                afr[ks] = *(const f16x8*)(bufA + mts + ks * 1024 + rb[ks]);
            __syncthreads();               // bufs reused as fval below
            loadUV(tile + gridDim.x);
            f32x16 ah = {}, al2 = {};
#pragma unroll
            for (int ks = 0; ks < 4; ++ks) {
                ah  = MFMA(afr[ks], *(const f16x8*)(sAB + 2 * 4096 + ntw * 2048 + ks * 512 + l * 8), ah, 0, 0, 0);
                al2 = MFMA(afr[ks], *(const f16x8*)(sAB + 3 * 4096 + ntw * 2048 + ks * 512 + l * 8), al2, 0, 0, 0);
            }
#pragma unroll
            for (int r = 0; r < 16; ++r) {
                int lr2 = (r & 3) + 8 * (r >> 2) + 4 * kg;
                int row = mt * 32 + lr2;
                fval[row * 64 + ((ch + row) & 63)] = tanh_fast(ah[r] + al2[r]);
            }
        }
        __syncthreads();

        // ---- P5: segmented reduce over sorted-i runs; ONE atomic per (segment, ch)
        {
            int ch2 = tid & 63;
            for (int s = tid >> 6; s < nLead; s += 12) {
                int lr = leadRow[s];
                int id = sIdx[lr];
                if (id == SENT) continue;
                float sum = 0.f;
                int r = lr;
                do {
                    sum += fval[r * 64 + ((ch2 + r) & 63)];
                    ++r;
                } while (r < TILE && sIdx[r] == id);
                atomicAdd(&accp[id * 64 + ch2], sum);
            }
        }
        __syncthreads();
    }
}

extern "C" void kernel_launch(void* const* d_in, const int* in_sizes, int n_in,
                              void* d_out, int out_size, void* d_ws, size_t ws_size,
                              hipStream_t stream) {
    const int* ind2 = (const int*)d_in[0];
    const float* prop = (const float*)d_in[1];
    const float* basis = (const float*)d_in[2];
    const float* pp0_w1 = (const float*)d_in[3];
    const float* pp0_b1 = (const float*)d_in[4];
    const float* pp_w1 = (const float*)d_in[5];
    const float* pp_b1 = (const float*)d_in[6];
    const float* pp_w2 = (const float*)d_in[7];
    const float* pp_b2 = (const float*)d_in[8];
    const float* pi_w1 = (const float*)d_in[9];
    const float* pi_b1 = (const float*)d_in[10];
    const float* pi_w2 = (const float*)d_in[11];
    const float* pi_b2 = (const float*)d_in[12];
    const float* ii_w1 = (const float*)d_in[13];
    const float* ii_w2 = (const float*)d_in[14];
    const float* res0_w = (const float*)d_in[15];
    const float* out_w1 = (const float*)d_in[16];
    const float* out_b1 = (const float*)d_in[17];
    const float* out_w2 = (const float*)d_in[18];
    const float* out_b2 = (const float*)d_in[19];
    const float* out_wo = (const float*)d_in[20];
    float* out = (float*)d_out;

    // workspace layout
    float* B0 = (float*)d_ws;                            // 25000*64 f32
    float* B1 = B0 + N_ATOMS * 64;
    float* Ubuf = B1 + N_ATOMS * 64;
    float* Vbuf = Ubuf + N_ATOMS * 64;
    float4* sBas4 = (float4*)(Vbuf + N_ATOMS * 64);      // 500000 float4 (16B-aligned)
    int2* sIJ = (int2*)(sBas4 + N_PAIRS);                // 500000 int2
    u16* img1 = (u16*)(sIJ + N_PAIRS);                   // 4*16384 u16
    u16* img2 = img1 + 4 * 16384;                        // 4*32768 u16
    u16* imgab = img2 + 4 * 32768;                       // 4*16384 u16
    float* b2p = (float*)(imgab + 4 * 16384);            // 4*256 f32
    u32* hist = (u32*)(b2p + 1024);                      // 25024 u32
    u32* cursor = hist + 25024;                          // 25024 u32
    float* pbuf[2] = {B0, B1};

    // counting sort of pairs by ind_i (reused by all 4 depths)
    zero_hist<<<98, 256, 0, stream>>>(hist);
    hist_kernel<<<(N_PAIRS + 255) / 256, 256, 0, stream>>>(ind2, hist);
    scan_kernel<<<1, 1024, 0, stream>>>(hist, cursor);
    scatter_kernel<<<(N_PAIRS + 255) / 256, 256, 0, stream>>>(ind2, basis, cursor, sIJ, sBas4);

    prep_kernel<<<512, 256, 0, stream>>>(pi_w1, pi_w2, ii_w1, ii_w2, img1, img2, imgab);
    prep_b2<<<4, 256, 0, stream>>>(pi_b2, b2p);

    const int ablocks = (N_ATOMS + 15) / 16;
    for (int d = 0; d < DEPTH; ++d) {
        float* acc = pbuf[d & 1];
        if (d == 0) {
            atom_mlp<16, true><<<ablocks, 256, 0, stream>>>(
                prop, pp0_w1, pp0_b1, pp_w2, pp_b2, res0_w,
                pi_w1, Ubuf, Vbuf, acc);
        } else {
            const float* pin = pbuf[(d - 1) & 1];
            fused_out_atom<<<ablocks, 256, 0, stream>>>(
                pin,
                out_w1 + (d - 1) * 4096, out_b1 + (d - 1) * 64,
                out_w2 + (d - 1) * 4096, out_b2 + (d - 1) * 64, out_wo + (d - 1) * 64,
                pp_w1 + (d - 1) * 4096, pp_b1 + (d - 1) * 64,
                pp_w2 + d * 4096, pp_b2 + d * 64,
                out, (d - 1) == 0 ? 1 : 0,
                pi_w1 + d * 8192, Ubuf, Vbuf, acc);
        }
        pair_kernel<<<256, PTHREADS, 0, stream>>>(
            Ubuf, Vbuf, sIJ, sBas4,
            img2 + d * 32768, imgab + d * 16384,
            pi_b1 + d * 64, b2p + d * 256, acc);
    }
    out_kernel<<<ablocks, 256, 0, stream>>>(
        pbuf[(DEPTH - 1) & 1], out_w1 + (DEPTH - 1) * 4096, out_b1 + (DEPTH - 1) * 64,
        out_w2 + (DEPTH - 1) * 4096, out_b2 + (DEPTH - 1) * 64, out_wo + (DEPTH - 1) * 64,
        out, 0);
}

// Round 7
// 1289.982 us; speedup vs baseline: 1.3264x; 1.3264x over previous
//
#include <hip/hip_runtime.h>
#include <hip/hip_bf16.h>

#define N_ATOMS 25000
#define N_PAIRS 500000
#define DEPTH 4
#define TILE 192
#define PTHREADS 768
#define SENT 0x7fffffff

typedef _Float16 f16x8 __attribute__((ext_vector_type(8)));
typedef float f32x16 __attribute__((ext_vector_type(16)));
typedef unsigned short u16;
typedef unsigned int u32;

__device__ __forceinline__ float tanh_fast(float x) {
    // tanh(x) = 1 - 2/(exp(2x)+1); saturates correctly at +/-inf
    float e = __expf(2.0f * x);
    return 1.0f - 2.0f * __builtin_amdgcn_rcpf(e + 1.0f);
}

__device__ __forceinline__ void split_h(float x, u16& hi, u16& lo) {
    _Float16 h = (_Float16)x;                 // RNE
    _Float16 l = (_Float16)(x - (float)h);    // residual, RNE
    hi = *(u16*)&h;
    lo = *(u16*)&l;
}

// LDS bank-swizzle on 16B-unit index (involution within 128B block).
// Verified: SQ_LDS_BANK_CONFLICT 2.02e7 -> 0 (rounds 1-3).
__device__ __forceinline__ int swz8(int u) { return u ^ ((u >> 5) & 7); }

// ---------------- prep: split weights to hi/lo fp16, fragment-major images
__global__ __launch_bounds__(256)
void prep_kernel(const float* __restrict__ piW1, const float* __restrict__ piW2,
                 const float* __restrict__ iiW1, const float* __restrict__ iiW2,
                 u16* __restrict__ img1, u16* __restrict__ img2, u16* __restrict__ imgab) {
    int gid = blockIdx.x * 256 + threadIdx.x;
    int d = gid >> 15, e = gid & 32767;
    u16 hi, lo;
    if (e < 8192) {                 // W1 [k=128][n=64] (unused by pair since R5)
        int k = e >> 6, n = e & 63;
        split_h(piW1[d * 8192 + e], hi, lo);
        int ntw = n >> 5, colb = n & 31;
        int ks = k >> 4, lh = (k >> 3) & 1, j = k & 7;
        int off = ((ntw * 8 + ks) * 64 + lh * 32 + colb) * 8 + j;
        img1[d * 16384 + 0 * 8192 + off] = hi;
        img1[d * 16384 + 1 * 8192 + off] = lo;
    } else if (e < 24576) {         // W2 [k=64][n=256], permuted n = 4*ch + t
        int s = e - 8192;
        int k = s >> 8, n = s & 255;
        split_h(piW2[d * 16384 + s], hi, lo);
        int ch = n >> 2, t = n & 3;
        int ntw = ch >> 5, colb = ch & 31;
        int ks = k >> 4, lh = (k >> 3) & 1, j = k & 7;
        int off = (((ntw * 4 + t) * 4 + ks) * 64 + lh * 32 + colb) * 8 + j;
        img2[d * 32768 + 0 * 16384 + off] = hi;
        img2[d * 32768 + 1 * 16384 + off] = lo;
    } else {                        // Wa (stage0) / Wb (stage1), [k=64][n=64]
        int stage = (e < 28672) ? 0 : 1;
        int s = e - (stage ? 28672 : 24576);
        int k = s >> 6, n = s & 63;
        float x = stage ? iiW2[d * 4096 + s] : iiW1[d * 4096 + s];
        split_h(x, hi, lo);
        int ntw = n >> 5, colb = n & 31;
        int ks = k >> 4, lh = (k >> 3) & 1, j = k & 7;
        int off = ((ntw * 4 + ks) * 64 + lh * 32 + colb) * 8 + j;
        imgab[d * 16384 + (stage * 2 + 0) * 4096 + off] = hi;
        imgab[d * 16384 + (stage * 2 + 1) * 4096 + off] = lo;
    }
}

__global__ __launch_bounds__(256)
void prep_b2(const float* __restrict__ piB2, float* __restrict__ b2p) {
    int d = blockIdx.x, n = threadIdx.x;
    int ch = n >> 2, t = n & 3;
    int np = (ch >> 5) * 128 + t * 32 + (ch & 31);
    b2p[d * 256 + np] = piB2[d * 256 + n];
}

// ---------------- counting sort of pairs by ind_i (once per launch; reused all depths)
__global__ __launch_bounds__(256)
void zero_hist(u32* __restrict__ hist) {
    int i = blockIdx.x * 256 + threadIdx.x;
    if (i < 25024) hist[i] = 0u;
}

__global__ __launch_bounds__(256)
void hist_kernel(const int* __restrict__ ind2, u32* __restrict__ hist) {
    int p = blockIdx.x * 256 + threadIdx.x;
    if (p < N_PAIRS) atomicAdd(&hist[ind2[2 * p]], 1u);
}

__global__ __launch_bounds__(1024)
void scan_kernel(const u32* __restrict__ hist, u32* __restrict__ cursor) {
    __shared__ u32 sdata[1024];
    __shared__ u32 stotal;
    int t = threadIdx.x;
    if (t == 0) stotal = 0u;
    __syncthreads();
    for (int cch = 0; cch < 25; ++cch) {     // 25*1024 >= 25000
        int idx = cch * 1024 + t;
        u32 v = (idx < N_ATOMS) ? hist[idx] : 0u;
        sdata[t] = v;
        __syncthreads();
        for (int off = 1; off < 1024; off <<= 1) {
            u32 x = (t >= off) ? sdata[t - off] : 0u;
            __syncthreads();
            sdata[t] += x;
            __syncthreads();
        }
        u32 excl = sdata[t] - v;
        u32 tot = stotal;
        if (idx < N_ATOMS) cursor[idx] = tot + excl;
        u32 chunktot = sdata[1023];
        __syncthreads();
        if (t == 0) stotal = tot + chunktot;
        __syncthreads();
    }
}

__global__ __launch_bounds__(256)
void scatter_kernel(const int* __restrict__ ind2, const float* __restrict__ basis,
                    u32* __restrict__ cursor, int2* __restrict__ sIJ,
                    float4* __restrict__ sBas4) {
    int p = blockIdx.x * 256 + threadIdx.x;
    if (p >= N_PAIRS) return;
    int i = ind2[2 * p], j = ind2[2 * p + 1];
    u32 pos = atomicAdd(&cursor[i], 1u);
    sIJ[pos] = make_int2(i, j);
    sBas4[pos] = ((const float4*)basis)[p];
}

// ---------------- atom-level MLP (R5 version: 4 atoms/block, no spill); emits U,V
template <int K, bool IS_D0>
__global__ __launch_bounds__(256)
void atom_mlp(const float* __restrict__ p_in,
              const float* __restrict__ W1, const float* __restrict__ b1,
              const float* __restrict__ W2, const float* __restrict__ b2,
              const float* __restrict__ res0_w,
              const float* __restrict__ piW1d,
              float* __restrict__ Uo, float* __restrict__ Vo,
              float* __restrict__ acc_out) {
    __shared__ float sP[4][64];
    __shared__ float sH[4][64];
    __shared__ float sH2[4][64];
    int tid = threadIdx.x;
    int al = tid >> 6, c = tid & 63;
    int a = blockIdx.x * 4 + al;
    if (c < K) sP[al][c] = p_in[a * K + c];
    __syncthreads();
    float s = b1[c];
#pragma unroll
    for (int k = 0; k < K; ++k) s += sP[al][k] * W1[k * 64 + c];
    float t1 = tanh_fast(s);
    float r;
    if (IS_D0) {
        r = 0.f;
#pragma unroll
        for (int k = 0; k < 16; ++k) r += sP[al][k] * res0_w[k * 64 + c];
    } else {
        r = sP[al][c];
    }
    acc_out[a * 64 + c] = r;
    sH[al][c] = t1;
    __syncthreads();
    float s2 = b2[c];
#pragma unroll
    for (int k = 0; k < 64; ++k) s2 += sH[al][k] * W2[k * 64 + c];
    float hv = tanh_fast(s2);
    sH2[al][c] = hv;
    __syncthreads();
    float su = 0.f, sv = 0.f;
#pragma unroll
    for (int k = 0; k < 64; ++k) {
        float x = sH2[al][k];
        su += x * piW1d[k * 64 + c];
        sv += x * piW1d[(64 + k) * 64 + c];
    }
    Uo[a * 64 + c] = su;
    Vo[a * 64 + c] = sv;
}

// ---------------- output head (fp32), standalone (after last depth) — R5 version
__global__ __launch_bounds__(256)
void out_kernel(const float* __restrict__ p,
                const float* __restrict__ W1, const float* __restrict__ b1,
                const float* __restrict__ W2, const float* __restrict__ b2,
                const float* __restrict__ wo,
                float* __restrict__ out, int store) {
    __shared__ float sP[4][64];
    __shared__ float sH[4][64];
    int tid = threadIdx.x;
    int al = tid >> 6, c = tid & 63;
    int a = blockIdx.x * 4 + al;
    sP[al][c] = p[a * 64 + c];
    __syncthreads();
    float s = b1[c];
#pragma unroll
    for (int k = 0; k < 64; ++k) s += sP[al][k] * W1[k * 64 + c];
    sH[al][c] = tanh_fast(s);
    __syncthreads();
    float s2 = b2[c];
#pragma unroll
    for (int k = 0; k < 64; ++k) s2 += sH[al][k] * W2[k * 64 + c];
    float v = tanh_fast(s2) * wo[c];
#pragma unroll
    for (int off = 32; off > 0; off >>= 1) v += __shfl_down(v, off, 64);
    if (c == 0) {
        if (store) out[a] = v;
        else out[a] += v;
    }
}

// ---------------- fused: out head of depth d + atom MLP of depth d+1 (+U/V) — R5 version
__global__ __launch_bounds__(256)
void fused_out_atom(const float* __restrict__ p,
                    const float* __restrict__ oW1, const float* __restrict__ ob1,
                    const float* __restrict__ oW2, const float* __restrict__ ob2,
                    const float* __restrict__ wo,
                    const float* __restrict__ aW1, const float* __restrict__ ab1,
                    const float* __restrict__ aW2, const float* __restrict__ ab2,
                    float* __restrict__ out, int store,
                    const float* __restrict__ piW1d,
                    float* __restrict__ Uo, float* __restrict__ Vo,
                    float* __restrict__ acc_out) {
    __shared__ float sP[4][64];
    __shared__ float sHo[4][64];
    __shared__ float sHa[4][64];
    int tid = threadIdx.x;
    int al = tid >> 6, c = tid & 63;
    int a = blockIdx.x * 4 + al;
    float pv = p[a * 64 + c];
    sP[al][c] = pv;
    acc_out[a * 64 + c] = pv;            // residual base for next depth
    __syncthreads();
    float so = ob1[c], sa = ab1[c];
#pragma unroll
    for (int k = 0; k < 64; ++k) {
        float x = sP[al][k];
        so += x * oW1[k * 64 + c];
        sa += x * aW1[k * 64 + c];
    }
    sHo[al][c] = tanh_fast(so);
    sHa[al][c] = tanh_fast(sa);
    __syncthreads();
    float s2o = ob2[c], s2a = ab2[c];
#pragma unroll
    for (int k = 0; k < 64; ++k) {
        s2o += sHo[al][k] * oW2[k * 64 + c];
        s2a += sHa[al][k] * aW2[k * 64 + c];
    }
    float v = tanh_fast(s2o) * wo[c];
#pragma unroll
    for (int off = 32; off > 0; off >>= 1) v += __shfl_down(v, off, 64);
    if (c == 0) {
        if (store) out[a] = v;
        else out[a] += v;
    }
    float hv = tanh_fast(s2a);
    sP[al][c] = hv;                      // sP dead after loop1; reuse for h
    __syncthreads();
    float su = 0.f, sv = 0.f;
#pragma unroll
    for (int k = 0; k < 64; ++k) {
        float x = sP[al][k];
        su += x * piW1d[k * 64 + c];
        sv += x * piW1d[(64 + k) * 64 + c];
    }
    Uo[a * 64 + c] = su;
    Vo[a * 64 + c] = sv;
}

// ---------------- pair pipeline v3: sorted pairs, segment-reduced scatter
#define MFMA __builtin_amdgcn_mfma_f32_32x32x16_f16

__global__ __launch_bounds__(PTHREADS, 3)
void pair_kernel(const float* __restrict__ Uin,
                 const float* __restrict__ Vin,
                 const int2* __restrict__ sIJ,
                 const float4* __restrict__ sBas4,
                 const u16* __restrict__ img2,
                 const u16* __restrict__ imgab,
                 const float* __restrict__ piB1,
                 const float* __restrict__ b2p,
                 float* __restrict__ accp) {
    __shared__ __attribute__((aligned(16))) _Float16 sW2[32768];   // 64 KB
    __shared__ __attribute__((aligned(16))) u16 sAB[16384];        // 32 KB
    __shared__ __attribute__((aligned(16))) _Float16 bufs[24576];  // 48 KB: bufA|bufB, fval f32 view
    __shared__ float sBas[TILE * 4];                               //  3 KB
    __shared__ int sIdx[TILE];                                     // 0.75 KB
    __shared__ unsigned short leadRow[TILE];                       // 0.38 KB
    __shared__ int nLead;
    // total ~148 KB -> 1 block/CU, 12 waves = 3 waves/SIMD

    const int tid = threadIdx.x;
    for (int i = tid; i < 4096; i += PTHREADS) ((uint4*)sW2)[i] = ((const uint4*)img2)[i];
    for (int i = tid; i < 2048; i += PTHREADS) ((uint4*)sAB)[i] = ((const uint4*)imgab)[i];

    char* bufA = (char*)bufs;
    char* bufB = (char*)bufs + 24576;
    float* fval = (float*)bufs;            // [192][64] rotated: fval[r*64 + ((ch+r)&63)]

    const int l = tid & 63;
    const int w = tid >> 6;
    const int mt = w >> 1, ntw = w & 1;
    const int col = l & 31, kg = l >> 5;
    const int ch = ntw * 32 + col;
    const int chks = ch >> 4, chlh = (ch >> 3) & 1, chj = ch & 7;

    int rb[4], wb[4];
    {
        const int wxor = 2 * chks + chlh;
#pragma unroll
        for (int c = 0; c < 4; ++c) {
            rb[c] = (l ^ (kg + 2 * c)) << 4;
            wb[c] = (mt * 4 + chks) * 1024 + chlh * 512 + ((((c) + 4 * kg) ^ wxor) << 4) + chj * 2;
        }
    }
    const int mts = mt << 12;

    const int m = tid >> 2, ksel = tid & 3;
    const int mtd = m >> 5, lrow = m & 31;
    const int u0 = (mtd * 4 + ksel) * 64 + lrow;
    const int wA0 = swz8(u0) * 16, wA1 = swz8(u0 + 32) * 16;

    float b1p[16];
#pragma unroll
    for (int z = 0; z < 16; ++z) b1p[z] = piB1[ksel * 16 + z];
    float b2v[4];
#pragma unroll
    for (int t = 0; t < 4; ++t) b2v[t] = b2p[ntw * 128 + t * 32 + col];

    const int nTiles = (N_PAIRS + TILE - 1) / TILE;

    float ur[16], vr[16];
    auto loadUV = [&](int tile) {
        int p = tile * TILE + m;
        bool ok = (p < N_PAIRS);
        int2 ij = ok ? sIJ[p] : make_int2(0, 0);
        const float* up = Uin + ij.x * 64 + ksel * 16;
        const float* vp = Vin + ij.y * 64 + ksel * 16;
        float4 z4 = make_float4(0.f, 0.f, 0.f, 0.f);
#pragma unroll
        for (int q = 0; q < 4; ++q) {
            float4 a = ok ? *(const float4*)(up + q * 4) : z4;
            float4 b = ok ? *(const float4*)(vp + q * 4) : z4;
            ur[q * 4 + 0] = a.x; ur[q * 4 + 1] = a.y; ur[q * 4 + 2] = a.z; ur[q * 4 + 3] = a.w;
            vr[q * 4 + 0] = b.x; vr[q * 4 + 1] = b.y; vr[q * 4 + 2] = b.z; vr[q * 4 + 3] = b.w;
        }
    };
    loadUV(blockIdx.x);

    for (int tile = blockIdx.x; tile < nTiles; tile += gridDim.x) {
        const int base = tile * TILE;

        // ---- P1: stage basis/sorted-i; G1out = tanh(U[i]+V[j]+b1) -> bufA frags
        if (tid < TILE) {
            int p = base + tid;
            bool ok = p < N_PAIRS;
            float4 bv = ok ? sBas4[p] : make_float4(0.f, 0.f, 0.f, 0.f);
            *(float4*)&sBas[tid * 4] = bv;
            sIdx[tid] = ok ? sIJ[p].x : SENT;
        }
        if (tid == 255) nLead = 0;
        {
            f16x8 lo8, hi8;
#pragma unroll
            for (int z = 0; z < 8; ++z)
                lo8[z] = (_Float16)tanh_fast(ur[z] + vr[z] + b1p[z]);
#pragma unroll
            for (int z = 0; z < 8; ++z)
                hi8[z] = (_Float16)tanh_fast(ur[8 + z] + vr[8 + z] + b1p[8 + z]);
            *(f16x8*)(bufA + wA0) = lo8;
            *(f16x8*)(bufA + wA1) = hi8;
        }
        __syncthreads();

        // ---- P2: build segment-leader list; [192x64]@[64x256]+b2, tanh, basis contraction -> bufB
        if (tid < TILE) {
            int id = sIdx[tid];
            if (tid == 0 || id != sIdx[tid - 1]) {
                int k = atomicAdd(&nLead, 1);
                leadRow[k] = (unsigned short)tid;
            }
        }
        {
            f16x8 afr[4];
#pragma unroll
            for (int ks = 0; ks < 4; ++ks)
                afr[ks] = *(const f16x8*)(bufA + mts + ks * 1024 + rb[ks]);
            float s[16];
#pragma unroll
            for (int r = 0; r < 16; ++r) s[r] = 0.f;
#pragma unroll
            for (int pp = 0; pp < 2; ++pp) {
                f32x16 a0 = {}, a1 = {};
                const int t0 = 2 * pp, t1 = 2 * pp + 1;
#pragma unroll
                for (int ks = 0; ks < 4; ++ks) {
                    a0 = MFMA(afr[ks], *(const f16x8*)(sW2 + ((ntw * 4 + t0) * 4 + ks) * 512 + l * 8), a0, 0, 0, 0);
                    a0 = MFMA(afr[ks], *(const f16x8*)(sW2 + 16384 + ((ntw * 4 + t0) * 4 + ks) * 512 + l * 8), a0, 0, 0, 0);
                    a1 = MFMA(afr[ks], *(const f16x8*)(sW2 + ((ntw * 4 + t1) * 4 + ks) * 512 + l * 8), a1, 0, 0, 0);
                    a1 = MFMA(afr[ks], *(const f16x8*)(sW2 + 16384 + ((ntw * 4 + t1) * 4 + ks) * 512 + l * 8), a1, 0, 0, 0);
                }
#pragma unroll
                for (int r = 0; r < 16; ++r) {
                    int lr2 = (r & 3) + 8 * (r >> 2) + 4 * kg;
                    int row = mt * 32 + lr2;
                    float2 bb = *(const float2*)&sBas[row * 4 + 2 * pp];
                    s[r] += tanh_fast(a0[r] + b2v[t0]) * bb.x + tanh_fast(a1[r] + b2v[t1]) * bb.y;
                }
            }
#pragma unroll
            for (int r = 0; r < 16; ++r)
                *(u16*)(bufB + wb[r & 3] + ((r >> 2) << 7)) =
                    __builtin_bit_cast(u16, (_Float16)s[r]);
        }
        __syncthreads();

        // ---- P3: inter @ ii_w1 (hi+lo), tanh -> bufA
        {
            f32x16 ah = {}, al2 = {};
#pragma unroll
            for (int ks = 0; ks < 4; ++ks) {
                f16x8 a = *(const f16x8*)(bufB + mts + ks * 1024 + rb[ks]);
                ah  = MFMA(a, *(const f16x8*)(sAB + 0 * 4096 + ntw * 2048 + ks * 512 + l * 8), ah, 0, 0, 0);
                al2 = MFMA(a, *(const f16x8*)(sAB + 1 * 4096 + ntw * 2048 + ks * 512 + l * 8), al2, 0, 0, 0);
            }
#pragma unroll
            for (int r = 0; r < 16; ++r)
                *(u16*)(bufA + wb[r & 3] + ((r >> 2) << 7)) =
                    __builtin_bit_cast(u16, (_Float16)tanh_fast(ah[r] + al2[r]));
        }
        __syncthreads();

        // ---- P4: @ ii_w2, tanh -> f32 LDS tile (rotated); prefetch next-tile U/V
        {
            f16x8 afr[4];
#pragma unroll
            for (int ks = 0; ks < 4; ++ks)
                afr[ks] = *(const f16x8*)(bufA + mts + ks * 1024 + rb[ks]);
            __syncthreads();               // bufs reused as fval below
            loadUV(tile + gridDim.x);
            f32x16 ah = {}, al2 = {};
#pragma unroll
            for (int ks = 0; ks < 4; ++ks) {
                ah  = MFMA(afr[ks], *(const f16x8*)(sAB + 2 * 4096 + ntw * 2048 + ks * 512 + l * 8), ah, 0, 0, 0);
                al2 = MFMA(afr[ks], *(const f16x8*)(sAB + 3 * 4096 + ntw * 2048 + ks * 512 + l * 8), al2, 0, 0, 0);
            }
#pragma unroll
            for (int r = 0; r < 16; ++r) {
                int lr2 = (r & 3) + 8 * (r >> 2) + 4 * kg;
                int row = mt * 32 + lr2;
                fval[row * 64 + ((ch + row) & 63)] = tanh_fast(ah[r] + al2[r]);
            }
        }
        __syncthreads();

        // ---- P5: segmented reduce over sorted-i runs; ONE atomic per (segment, ch)
        {
            int ch2 = tid & 63;
            for (int s = tid >> 6; s < nLead; s += 12) {
                int lr = leadRow[s];
                int id = sIdx[lr];
                if (id == SENT) continue;
                float sum = 0.f;
                int r = lr;
                do {
                    sum += fval[r * 64 + ((ch2 + r) & 63)];
                    ++r;
                } while (r < TILE && sIdx[r] == id);
                atomicAdd(&accp[id * 64 + ch2], sum);
            }
        }
        __syncthreads();
    }
}

extern "C" void kernel_launch(void* const* d_in, const int* in_sizes, int n_in,
                              void* d_out, int out_size, void* d_ws, size_t ws_size,
                              hipStream_t stream) {
    const int* ind2 = (const int*)d_in[0];
    const float* prop = (const float*)d_in[1];
    const float* basis = (const float*)d_in[2];
    const float* pp0_w1 = (const float*)d_in[3];
    const float* pp0_b1 = (const float*)d_in[4];
    const float* pp_w1 = (const float*)d_in[5];
    const float* pp_b1 = (const float*)d_in[6];
    const float* pp_w2 = (const float*)d_in[7];
    const float* pp_b2 = (const float*)d_in[8];
    const float* pi_w1 = (const float*)d_in[9];
    const float* pi_b1 = (const float*)d_in[10];
    const float* pi_w2 = (const float*)d_in[11];
    const float* pi_b2 = (const float*)d_in[12];
    const float* ii_w1 = (const float*)d_in[13];
    const float* ii_w2 = (const float*)d_in[14];
    const float* res0_w = (const float*)d_in[15];
    const float* out_w1 = (const float*)d_in[16];
    const float* out_b1 = (const float*)d_in[17];
    const float* out_w2 = (const float*)d_in[18];
    const float* out_b2 = (const float*)d_in[19];
    const float* out_wo = (const float*)d_in[20];
    float* out = (float*)d_out;

    // workspace layout
    float* B0 = (float*)d_ws;                            // 25000*64 f32
    float* B1 = B0 + N_ATOMS * 64;
    float* Ubuf = B1 + N_ATOMS * 64;
    float* Vbuf = Ubuf + N_ATOMS * 64;
    float4* sBas4 = (float4*)(Vbuf + N_ATOMS * 64);      // 500000 float4 (16B-aligned)
    int2* sIJ = (int2*)(sBas4 + N_PAIRS);                // 500000 int2
    u16* img1 = (u16*)(sIJ + N_PAIRS);                   // 4*16384 u16
    u16* img2 = img1 + 4 * 16384;                        // 4*32768 u16
    u16* imgab = img2 + 4 * 32768;                       // 4*16384 u16
    float* b2p = (float*)(imgab + 4 * 16384);            // 4*256 f32
    u32* hist = (u32*)(b2p + 1024);                      // 25024 u32
    u32* cursor = hist + 25024;                          // 25024 u32
    float* pbuf[2] = {B0, B1};

    // counting sort of pairs by ind_i (reused by all 4 depths)
    zero_hist<<<98, 256, 0, stream>>>(hist);
    hist_kernel<<<(N_PAIRS + 255) / 256, 256, 0, stream>>>(ind2, hist);
    scan_kernel<<<1, 1024, 0, stream>>>(hist, cursor);
    scatter_kernel<<<(N_PAIRS + 255) / 256, 256, 0, stream>>>(ind2, basis, cursor, sIJ, sBas4);

    prep_kernel<<<512, 256, 0, stream>>>(pi_w1, pi_w2, ii_w1, ii_w2, img1, img2, imgab);
    prep_b2<<<4, 256, 0, stream>>>(pi_b2, b2p);

    for (int d = 0; d < DEPTH; ++d) {
        float* acc = pbuf[d & 1];
        if (d == 0) {
            atom_mlp<16, true><<<N_ATOMS / 4, 256, 0, stream>>>(
                prop, pp0_w1, pp0_b1, pp_w2, pp_b2, res0_w,
                pi_w1, Ubuf, Vbuf, acc);
        } else {
            const float* pin = pbuf[(d - 1) & 1];
            fused_out_atom<<<N_ATOMS / 4, 256, 0, stream>>>(
                pin,
                out_w1 + (d - 1) * 4096, out_b1 + (d - 1) * 64,
                out_w2 + (d - 1) * 4096, out_b2 + (d - 1) * 64, out_wo + (d - 1) * 64,
                pp_w1 + (d - 1) * 4096, pp_b1 + (d - 1) * 64,
                pp_w2 + d * 4096, pp_b2 + d * 64,
                out, (d - 1) == 0 ? 1 : 0,
                pi_w1 + d * 8192, Ubuf, Vbuf, acc);
        }
        pair_kernel<<<256, PTHREADS, 0, stream>>>(
            Ubuf, Vbuf, sIJ, sBas4,
            img2 + d * 32768, imgab + d * 16384,
            pi_b1 + d * 64, b2p + d * 256, acc);
    }
    out_kernel<<<N_ATOMS / 4, 256, 0, stream>>>(
        pbuf[(DEPTH - 1) & 1], out_w1 + (DEPTH - 1) * 4096, out_b1 + (DEPTH - 1) * 64,
        out_w2 + (DEPTH - 1) * 4096, out_b2 + (DEPTH - 1) * 64, out_wo + (DEPTH - 1) * 64,
        out, 0);
}